// Round 5
// baseline (350.712 us; speedup 1.0000x reference)
//
#include <hip/hip_runtime.h>
#include <cstddef>

#define NB_HEAD 16
#define HEAD_DIM 64
#define D_MODEL 1024
#define BATCH 2
#define SEQ 2048
#define MROWS (BATCH * SEQ)  // 4096

typedef __bf16 bf16x8 __attribute__((ext_vector_type(8)));
typedef __bf16 bf16x4 __attribute__((ext_vector_type(4)));
typedef float  f32x4  __attribute__((ext_vector_type(4)));

#define WELEMS ((size_t)D_MODEL * D_MODEL)   // 1M per z
#define XELEMS ((size_t)MROWS * HEAD_DIM * NB_HEAD)  // 4M per array

#define ASYNC16(g, l) __builtin_amdgcn_global_load_lds( \
    (const __attribute__((address_space(1))) void*)(g), \
    (__attribute__((address_space(3))) void*)(l), 16, 0, 0)

static __device__ __forceinline__ void split_bf16(float x, __bf16& h, __bf16& l) {
    h = (__bf16)x;
    l = (__bf16)(x - (float)h);
}

// ---------------------------------------------------------------------------
// W[K][N] fp32 -> Wt_hi[N][K], Wt_lo[N][K] bf16 split, per z in {Q,K,V}.
// ---------------------------------------------------------------------------
__global__ __launch_bounds__(256) void conv_wt_kernel(
    const float* __restrict__ W0, const float* __restrict__ W1,
    const float* __restrict__ W2,
    __bf16* __restrict__ hi, __bf16* __restrict__ lo)
{
    __shared__ float tile[64][65];
    const int t  = threadIdx.x;
    const int k0 = blockIdx.x * 64;
    const int n0 = blockIdx.y * 64;
    const int z  = blockIdx.z;
    const float* W = (z == 0) ? W0 : ((z == 1) ? W1 : W2);
    __bf16* hz = hi + (size_t)z * WELEMS;
    __bf16* lz = lo + (size_t)z * WELEMS;

    #pragma unroll
    for (int p = 0; p < 4; ++p) {
        const int e = (p * 256 + t) * 4;
        const int r = e >> 6, c = e & 63;
        const float4 v = *(const float4*)(W + (size_t)(k0 + r) * D_MODEL + n0 + c);
        tile[r][c] = v.x; tile[r][c + 1] = v.y; tile[r][c + 2] = v.z; tile[r][c + 3] = v.w;
    }
    __syncthreads();
    #pragma unroll
    for (int p = 0; p < 4; ++p) {
        const int e = (p * 256 + t) * 4;
        const int n = e >> 6, kc = e & 63;
        __bf16 h[4], l[4];
        #pragma unroll
        for (int u = 0; u < 4; ++u) split_bf16(tile[kc + u][n], h[u], l[u]);
        *(bf16x4*)(hz + (size_t)(n0 + n) * D_MODEL + k0 + kc) = (bf16x4){h[0], h[1], h[2], h[3]};
        *(bf16x4*)(lz + (size_t)(n0 + n) * D_MODEL + k0 + kc) = (bf16x4){l[0], l[1], l[2], l[3]};
    }
}

// ---------------------------------------------------------------------------
// Split-bf16 MFMA projection v3. C = Xh Wh + Xh Wl + Xl Wh.
// 64x128 tile (m x n), BK=32, 4 waves in 2x2 (32m x 64n each).
// A staged as RAW FP32 via async (fp32 = hi+lo in one load); split to bf16
// per-fragment after the LDS read (~60 VALU/wave/step, overlaps MFMA).
// B pre-split bf16 via async. All LDS in fragment order: every ds_read is a
// contiguous b128 at lane*16B — zero bank conflicts.
// Grid x = m-strip so the 8 n-blocks sharing an X strip land on one XCD.
// Masked strips (l0 >= len) skipped; attn reads of skipped strips see finite
// poison that is masked downstream.
// ---------------------------------------------------------------------------
__global__ __launch_bounds__(256) void proj_mfma_kernel(
    const float* __restrict__ X0, const float* __restrict__ X1,
    const float* __restrict__ X2,
    const __bf16* __restrict__ Wthi, const __bf16* __restrict__ Wtlo,
    const int* __restrict__ q_len, const int* __restrict__ v_len,
    __bf16* __restrict__ qhi, __bf16* __restrict__ qlo,
    __bf16* __restrict__ khi, __bf16* __restrict__ klo,
    __bf16* __restrict__ vthi, __bf16* __restrict__ vtlo)
{
    __shared__ __align__(16) float  As[4 * 512];            // 8 KB, 4 pages
    __shared__ __align__(16) __bf16 Bh[8 * 512], Bl[8 * 512]; // 8+8 KB, 8 pages

    const int t    = threadIdx.x;
    const int wave = t >> 6, lane = t & 63;
    const int li   = lane & 15, grp = lane >> 4;
    const int wm   = wave >> 1, wn = wave & 1;
    const int m0   = blockIdx.x * 64;
    const int n0   = blockIdx.y * 128;
    const int z    = blockIdx.z;
    const int bb   = m0 >> 11;
    const int l0   = m0 & (SEQ - 1);
    const int need = (z == 0) ? q_len[bb] : v_len[bb];
    if (l0 >= need) return;   // consumers only use masked garbage from here

    const float* X = (z == 0) ? X0 : ((z == 1) ? X1 : X2);
    const __bf16* Wh = Wthi + (size_t)z * WELEMS;
    const __bf16* Wl = Wtlo + (size_t)z * WELEMS;

    f32x4 acc[2][4] = {};

    for (int k0 = 0; k0 < D_MODEL; k0 += 32) {
        // ---- A page s=wave: rows m0+wave*16+li, k = k0+grp*8 (8 fp32 = 2x16B)
        {
            const float* g = X + (size_t)(m0 + wave * 16 + li) * D_MODEL + k0 + grp * 8;
            float* d = As + wave * 512 + lane * 4;      // front half: j=0..3
            ASYNC16(g, d);
            ASYNC16(g + 4, d + 256);                    // back half: j=4..7
        }
        // ---- B pages s2 = wave*2+p (hi and lo)
        #pragma unroll
        for (int p = 0; p < 2; ++p) {
            const int s2 = wave * 2 + p;
            const size_t gb = (size_t)(n0 + s2 * 16 + li) * D_MODEL + k0 + grp * 8;
            const int dst = s2 * 512 + lane * 8;
            ASYNC16(Wh + gb, &Bh[dst]);
            ASYNC16(Wl + gb, &Bl[dst]);
        }
        __syncthreads();   // drains vmcnt, then barrier

        // A frags: read fp32, split to hi/lo in VALU
        bf16x8 ah[2], al[2];
        #pragma unroll
        for (int i = 0; i < 2; ++i) {
            const float* p = As + (wm * 2 + i) * 512 + lane * 4;
            const f32x4 x0 = *(const f32x4*)p;
            const f32x4 x1 = *(const f32x4*)(p + 256);
            const float xs[8] = {x0[0], x0[1], x0[2], x0[3], x1[0], x1[1], x1[2], x1[3]};
            #pragma unroll
            for (int e = 0; e < 8; ++e) {
                __bf16 h_, l_;
                split_bf16(xs[e], h_, l_);
                ah[i][e] = h_; al[i][e] = l_;
            }
        }
        #pragma unroll
        for (int j = 0; j < 4; ++j) {
            const int off = (wn * 4 + j) * 512 + lane * 8;
            const bf16x8 bh = *(const bf16x8*)&Bh[off];
            const bf16x8 bl = *(const bf16x8*)&Bl[off];
            #pragma unroll
            for (int i = 0; i < 2; ++i) {
                acc[i][j] = __builtin_amdgcn_mfma_f32_16x16x32_bf16(ah[i], bh, acc[i][j], 0, 0, 0);
                acc[i][j] = __builtin_amdgcn_mfma_f32_16x16x32_bf16(ah[i], bl, acc[i][j], 0, 0, 0);
                acc[i][j] = __builtin_amdgcn_mfma_f32_16x16x32_bf16(al[i], bh, acc[i][j], 0, 0, 0);
            }
        }
        __syncthreads();   // all reads done before next staging overwrite
    }

    // Epilogue. C/D: col = li, row = grp*4 + r within each 16x16 tile.
    if (z < 2) {
        __bf16* oh = (z == 0) ? qhi : khi;
        __bf16* ol = (z == 0) ? qlo : klo;
        #pragma unroll
        for (int j = 0; j < 4; ++j) {
            const int cg = n0 + wn * 64 + j * 16 + li;
            const int hd = cg >> 6, d = cg & 63;
            #pragma unroll
            for (int i = 0; i < 2; ++i) {
                #pragma unroll
                for (int r = 0; r < 4; ++r) {
                    const int rg = m0 + wm * 32 + i * 16 + grp * 4 + r;
                    const int lg = rg & (SEQ - 1);
                    const size_t a = (((size_t)bb * NB_HEAD + hd) * SEQ + lg) * HEAD_DIM + d;
                    __bf16 h_, l_;
                    split_bf16(acc[i][j][r], h_, l_);
                    oh[a] = h_; ol[a] = l_;
                }
            }
        }
    } else {
        // V^T [bh][d][SEQ], pack 4 consecutive l per store
        #pragma unroll
        for (int j = 0; j < 4; ++j) {
            const int cg = n0 + wn * 64 + j * 16 + li;
            const int hd = cg >> 6, d = cg & 63;
            const size_t rowbase = ((size_t)(bb * NB_HEAD + hd) * HEAD_DIM + d) * SEQ;
            #pragma unroll
            for (int i = 0; i < 2; ++i) {
                const int lbase = l0 + wm * 32 + i * 16 + grp * 4;
                bf16x4 ph, pl;
                #pragma unroll
                for (int r = 0; r < 4; ++r) {
                    __bf16 h_, l_;
                    split_bf16(acc[i][j][r], h_, l_);
                    ph[r] = h_; pl[r] = l_;
                }
                *(bf16x4*)(vthi + rowbase + lbase) = ph;
                *(bf16x4*)(vtlo + rowbase + lbase) = pl;
            }
        }
    }
}

// ---------------------------------------------------------------------------
// MFMA flash attention. blockIdx.x = head (XCD colocation of K/V),
// blockIdx.y = q-strip. Otherwise identical to round 3/4 version.
// ---------------------------------------------------------------------------
__global__ __launch_bounds__(256) void attn_mfma_kernel(
    const __bf16* __restrict__ qhi, const __bf16* __restrict__ qlo,
    const __bf16* __restrict__ khi, const __bf16* __restrict__ klo,
    const __bf16* __restrict__ vthi, const __bf16* __restrict__ vtlo,
    const int* __restrict__ q_len, const int* __restrict__ v_len,
    float* __restrict__ out)
{
    __shared__ __align__(16) __bf16 Khi[64 * 64], Klo[64 * 64];
    __shared__ __align__(16) __bf16 Vhi[64 * 64], Vlo[64 * 64];
    __shared__ __align__(16) __bf16 Ps[128][72];

    const int t = threadIdx.x;
    const int wq = t >> 6, lane = t & 63;
    const int grp = lane >> 4, li = lane & 15;
    const int hh = blockIdx.x;
    const int q0 = blockIdx.y * 128;
    const int b  = blockIdx.z;
    const int qlen = q_len[b], vlen = v_len[b];
    const int bh = b * NB_HEAD + hh;

    if (q0 >= qlen) {
        const int row = t >> 1, cs = (t & 1) * 32;
        float* o = out + ((size_t)b * SEQ + q0 + row) * D_MODEL + hh * HEAD_DIM + cs;
        const float4 z = make_float4(0.f, 0.f, 0.f, 0.f);
        #pragma unroll
        for (int u = 0; u < 8; ++u) *(float4*)(o + u * 4) = z;
        return;
    }

    const size_t koff = (size_t)bh * SEQ * HEAD_DIM;
    const int qbase = q0 + wq * 32;

    bf16x8 qh[2][2], ql[2][2];
    #pragma unroll
    for (int s = 0; s < 2; ++s) {
        #pragma unroll
        for (int ks = 0; ks < 2; ++ks) {
            const size_t a = koff + (size_t)(qbase + s * 16 + li) * HEAD_DIM + ks * 32 + grp * 8;
            qh[s][ks] = *(const bf16x8*)(qhi + a);
            ql[s][ks] = *(const bf16x8*)(qlo + a);
        }
    }

    f32x4 O[2][4] = {};
    float m_s[2][4], l_s[2][4];
    #pragma unroll
    for (int s = 0; s < 2; ++s)
        #pragma unroll
        for (int r = 0; r < 4; ++r) { m_s[s][r] = -1e30f; l_s[s][r] = 0.f; }

    const int srow = t >> 3, cpos = t & 7;
    const int nkt = (vlen + 63) >> 6;

    for (int tt = 0; tt < nkt; ++tt) {
        const int k0 = tt * 64;
        __syncthreads();

        #pragma unroll
        for (int h2 = 0; h2 < 2; ++h2) {
            const int r = h2 * 32 + srow;
            const int c = cpos ^ (r & 7);
            const size_t gk = koff + (size_t)(k0 + r) * HEAD_DIM + c * 8;
            const size_t gv = ((size_t)bh * HEAD_DIM + r) * SEQ + k0 + c * 8;
            const int dst = h2 * 2048 + t * 8;
            ASYNC16(khi + gk, &Khi[dst]);
            ASYNC16(klo + gk, &Klo[dst]);
            ASYNC16(vthi + gv, &Vhi[dst]);
            ASYNC16(vtlo + gv, &Vlo[dst]);
        }
        __syncthreads();

        f32x4 sacc[2][4] = {};
        #pragma unroll
        for (int ks = 0; ks < 2; ++ks) {
            #pragma unroll
            for (int j = 0; j < 4; ++j) {
                const int off = (j * 16 + li) * 64 + (((ks * 4 + grp) ^ (li & 7)) * 8);
                const bf16x8 kh_ = *(const bf16x8*)&Khi[off];
                const bf16x8 kl_ = *(const bf16x8*)&Klo[off];
                #pragma unroll
                for (int s = 0; s < 2; ++s) {
                    sacc[s][j] = __builtin_amdgcn_mfma_f32_16x16x32_bf16(qh[s][ks], kh_, sacc[s][j], 0, 0, 0);
                    sacc[s][j] = __builtin_amdgcn_mfma_f32_16x16x32_bf16(qh[s][ks], kl_, sacc[s][j], 0, 0, 0);
                    sacc[s][j] = __builtin_amdgcn_mfma_f32_16x16x32_bf16(ql[s][ks], kh_, sacc[s][j], 0, 0, 0);
                }
            }
        }

        #pragma unroll
        for (int s = 0; s < 2; ++s) {
            float mx[4] = {-1e30f, -1e30f, -1e30f, -1e30f};
            #pragma unroll
            for (int j = 0; j < 4; ++j) {
                const int key = k0 + j * 16 + li;
                #pragma unroll
                for (int r = 0; r < 4; ++r) {
                    float v = sacc[s][j][r] * 0.125f;
                    if (key >= vlen) v = -1e30f;
                    sacc[s][j][r] = v;
                    mx[r] = fmaxf(mx[r], v);
                }
            }
            #pragma unroll
            for (int r = 0; r < 4; ++r) {
                mx[r] = fmaxf(mx[r], __shfl_xor(mx[r], 1));
                mx[r] = fmaxf(mx[r], __shfl_xor(mx[r], 2));
                mx[r] = fmaxf(mx[r], __shfl_xor(mx[r], 4));
                mx[r] = fmaxf(mx[r], __shfl_xor(mx[r], 8));
            }
            float al[4], sum[4];
            #pragma unroll
            for (int r = 0; r < 4; ++r) {
                const float mn = fmaxf(m_s[s][r], mx[r]);
                al[r] = __expf(m_s[s][r] - mn);
                m_s[s][r] = mn;
                sum[r] = 0.f;
            }
            #pragma unroll
            for (int j = 0; j < 4; ++j) {
                #pragma unroll
                for (int r = 0; r < 4; ++r) {
                    const float p = __expf(sacc[s][j][r] - m_s[s][r]);
                    const __bf16 pb = (__bf16)p;
                    sum[r] += (float)pb;
                    Ps[wq * 32 + s * 16 + grp * 4 + r][j * 16 + li] = pb;
                }
            }
            #pragma unroll
            for (int r = 0; r < 4; ++r) {
                sum[r] += __shfl_xor(sum[r], 1);
                sum[r] += __shfl_xor(sum[r], 2);
                sum[r] += __shfl_xor(sum[r], 4);
                sum[r] += __shfl_xor(sum[r], 8);
                l_s[s][r] = l_s[s][r] * al[r] + sum[r];
            }
            #pragma unroll
            for (int j = 0; j < 4; ++j)
                #pragma unroll
                for (int r = 0; r < 4; ++r) O[s][j][r] *= al[r];
        }
        asm volatile("s_waitcnt lgkmcnt(0)" ::: "memory");

        #pragma unroll
        for (int ks = 0; ks < 2; ++ks) {
            bf16x8 pa[2];
            #pragma unroll
            for (int s = 0; s < 2; ++s)
                pa[s] = *(const bf16x8*)&Ps[wq * 32 + s * 16 + li][ks * 32 + grp * 8];
            #pragma unroll
            for (int j = 0; j < 4; ++j) {
                const int off = (j * 16 + li) * 64 + (((ks * 4 + grp) ^ (li & 7)) * 8);
                const bf16x8 vh_ = *(const bf16x8*)&Vhi[off];
                const bf16x8 vl_ = *(const bf16x8*)&Vlo[off];
                #pragma unroll
                for (int s = 0; s < 2; ++s) {
                    O[s][j] = __builtin_amdgcn_mfma_f32_16x16x32_bf16(pa[s], vh_, O[s][j], 0, 0, 0);
                    O[s][j] = __builtin_amdgcn_mfma_f32_16x16x32_bf16(pa[s], vl_, O[s][j], 0, 0, 0);
                }
            }
        }
    }

    #pragma unroll
    for (int s = 0; s < 2; ++s) {
        #pragma unroll
        for (int r = 0; r < 4; ++r) {
            const int q = qbase + s * 16 + grp * 4 + r;
            const float inv = (q < qlen) ? 1.f / l_s[s][r] : 0.f;
            #pragma unroll
            for (int j = 0; j < 4; ++j)
                out[((size_t)b * SEQ + q) * D_MODEL + hh * HEAD_DIM + j * 16 + li] = O[s][j][r] * inv;
        }
    }
}

extern "C" void kernel_launch(void* const* d_in, const int* in_sizes, int n_in,
                              void* d_out, int out_size, void* d_ws, size_t ws_size,
                              hipStream_t stream)
{
    (void)in_sizes; (void)n_in; (void)out_size; (void)ws_size;
    const float* Q_seq = (const float*)d_in[0];
    const float* K_seq = (const float*)d_in[1];
    const float* V_seq = (const float*)d_in[2];
    const int*   q_len = (const int*)d_in[3];
    const int*   v_len = (const int*)d_in[4];
    const float* WQ    = (const float*)d_in[5];
    const float* WK    = (const float*)d_in[6];
    const float* WV    = (const float*)d_in[7];
    float* out = (float*)d_out;

    // Workspace (__bf16 elems): wt 2x3M + q/k hi/lo + vt hi/lo 6x4M = 30M = 60 MB
    __bf16* wthi = (__bf16*)d_ws;
    __bf16* wtlo = wthi + 3 * WELEMS;
    __bf16* qhi_ = wtlo + 3 * WELEMS;
    __bf16* qlo_ = qhi_ + XELEMS;
    __bf16* khi_ = qlo_ + XELEMS;
    __bf16* klo_ = khi_ + XELEMS;
    __bf16* vthi_ = klo_ + XELEMS;
    __bf16* vtlo_ = vthi_ + XELEMS;

    dim3 blk(256);

    dim3 cg(D_MODEL / 64, D_MODEL / 64, 3);     // (16,16,3)
    conv_wt_kernel<<<cg, blk, 0, stream>>>(WQ, WK, WV, wthi, wtlo);

    dim3 pg(MROWS / 64, D_MODEL / 128, 3);      // (64,8,3) = 1536 blocks, m on x
    proj_mfma_kernel<<<pg, blk, 0, stream>>>(Q_seq, K_seq, V_seq, wthi, wtlo,
                                             q_len, v_len,
                                             qhi_, qlo_, khi_, klo_, vthi_, vtlo_);

    dim3 ag(NB_HEAD, SEQ / 128, BATCH);         // (16,16,2), head on x
    attn_mfma_kernel<<<ag, blk, 0, stream>>>(qhi_, qlo_, khi_, klo_, vthi_, vtlo_,
                                             q_len, v_len, out);
}

// Round 6
// 304.472 us; speedup vs baseline: 1.1519x; 1.1519x over previous
//
#include <hip/hip_runtime.h>
#include <cstddef>

#define NB_HEAD 16
#define HEAD_DIM 64
#define D_MODEL 1024
#define BATCH 2
#define SEQ 2048
#define MROWS (BATCH * SEQ)  // 4096

typedef __bf16 bf16x8 __attribute__((ext_vector_type(8)));
typedef __bf16 bf16x4 __attribute__((ext_vector_type(4)));
typedef float  f32x4  __attribute__((ext_vector_type(4)));

#define XEL ((size_t)MROWS * D_MODEL)        // 4M elems per z
#define WEL ((size_t)D_MODEL * D_MODEL)      // 1M elems per z

// ---- chunk layouts: 16 rows x 32 k of bf16, 512 elems = 1 KB, ordered
// offset = ((k>>3)&3)*128 + (row&15)*8 + (k&7)  == lane*8+e with
// lane = grp*16+li, row=li, k = grp*8+e  (exact MFMA A/B fragment order).
static __device__ __forceinline__ size_t xchunk(int row, int k) {   // [row16][kc] grid, kc=0..31
    return ((size_t)(row >> 4) * 32 + (k >> 5)) * 512 + ((k >> 3) & 3) * 128 + (row & 15) * 8 + (k & 7);
}
static __device__ __forceinline__ size_t qkbase(int bh, int row16, int dc) {  // [bh][row16=128][dc=2]
    return ((size_t)(bh * 128 + row16) * 2 + dc) * 512;
}
static __device__ __forceinline__ size_t qkelem(int bh, int row, int d) {
    return qkbase(bh, row >> 4, d >> 5) + ((d >> 3) & 3) * 128 + (row & 15) * 8 + (d & 7);
}
static __device__ __forceinline__ size_t vbase(int bh, int d16, int kc) {     // [bh][d16=4][kc=64]
    return ((size_t)(bh * 4 + d16) * 64 + kc) * 512;
}
static __device__ __forceinline__ size_t velem(int bh, int d, int key) {
    return vbase(bh, d >> 4, key >> 5) + ((key >> 3) & 3) * 128 + (d & 15) * 8 + (key & 7);
}

static __device__ __forceinline__ void split_bf16(float x, __bf16& h, __bf16& l) {
    h = (__bf16)x;
    l = (__bf16)(x - (float)h);
}

// ---------------------------------------------------------------------------
// W[K][N] fp32 -> chunk-format Wh/Wl (per z), rows = n, k = k.
// ---------------------------------------------------------------------------
__global__ __launch_bounds__(256) void conv_wt_kernel(
    const float* __restrict__ W0, const float* __restrict__ W1,
    const float* __restrict__ W2,
    __bf16* __restrict__ hi, __bf16* __restrict__ lo)
{
    __shared__ float tile[64][65];
    const int t  = threadIdx.x;
    const int k0 = blockIdx.x * 64;
    const int n0 = blockIdx.y * 64;
    const int z  = blockIdx.z;
    const float* W = (z == 0) ? W0 : ((z == 1) ? W1 : W2);
    __bf16* hz = hi + (size_t)z * WEL;
    __bf16* lz = lo + (size_t)z * WEL;

    #pragma unroll
    for (int p = 0; p < 4; ++p) {
        const int e = (p * 256 + t) * 4;
        const int r = e >> 6, c = e & 63;
        const float4 v = *(const float4*)(W + (size_t)(k0 + r) * D_MODEL + n0 + c);
        tile[r][c] = v.x; tile[r][c + 1] = v.y; tile[r][c + 2] = v.z; tile[r][c + 3] = v.w;
    }
    __syncthreads();
    #pragma unroll
    for (int p = 0; p < 4; ++p) {
        const int e = (p * 256 + t) * 4;        // 4 consecutive k for row n
        const int n = e >> 6, kc = e & 63;
        __bf16 h[4], l[4];
        #pragma unroll
        for (int u = 0; u < 4; ++u) split_bf16(tile[kc + u][n], h[u], l[u]);
        const size_t a = xchunk(n0 + n, k0 + kc);   // (k%4==0 -> 4 contiguous)
        *(bf16x4*)(hz + a) = (bf16x4){h[0], h[1], h[2], h[3]};
        *(bf16x4*)(lz + a) = (bf16x4){l[0], l[1], l[2], l[3]};
    }
}

// ---------------------------------------------------------------------------
// X fp32 -> chunk-format Xh/Xl per z, with 128-row strip skip.
// ---------------------------------------------------------------------------
__global__ __launch_bounds__(256) void conv_x_kernel(
    const float* __restrict__ X0, const float* __restrict__ X1,
    const float* __restrict__ X2,
    const int* __restrict__ q_len, const int* __restrict__ v_len,
    __bf16* __restrict__ xhi, __bf16* __restrict__ xlo)
{
    const int z = blockIdx.y;
    const size_t e = ((size_t)blockIdx.x * 256 + threadIdx.x) * 8;
    const int l = (int)(e >> 10), k = (int)(e & 1023);
    const int bb = l >> 11, lb = l & (SEQ - 1);
    const int len = (z == 0) ? q_len[bb] : v_len[bb];
    if (lb >= ((len + 127) & ~127)) return;

    const float* X = (z == 0) ? X0 : ((z == 1) ? X1 : X2);
    const float4 v0 = *(const float4*)(X + e);
    const float4 v1 = *(const float4*)(X + e + 4);
    const float xs[8] = {v0.x, v0.y, v0.z, v0.w, v1.x, v1.y, v1.z, v1.w};
    bf16x8 h8, l8;
    #pragma unroll
    for (int u = 0; u < 8; ++u) { __bf16 h_, l_; split_bf16(xs[u], h_, l_); h8[u] = h_; l8[u] = l_; }
    const size_t a = z * XEL + xchunk(l, k);    // k%8==0 -> contiguous 8
    *(bf16x8*)(xhi + a) = h8;
    *(bf16x8*)(xlo + a) = l8;
}

// ---------------------------------------------------------------------------
// Barrier-free streaming MFMA projection. C = Xh Wh + Xh Wl + Xl Wh.
// 128x128 tile, BK=32, 4 waves 2x2 (64x64 each). ZERO LDS, ZERO barriers:
// fragments load straight from chunk-format global (coalesced 1 KB/instr,
// L2-served), depth-1 ping-pong prefetch; compiler pipelines with vmcnt(N).
// ---------------------------------------------------------------------------
__global__ __launch_bounds__(256, 2) void proj_mfma_kernel(
    const __bf16* __restrict__ Xhi, const __bf16* __restrict__ Xlo,
    const __bf16* __restrict__ Wchi, const __bf16* __restrict__ Wclo,
    const int* __restrict__ q_len, const int* __restrict__ v_len,
    __bf16* __restrict__ qch, __bf16* __restrict__ qcl,
    __bf16* __restrict__ kch, __bf16* __restrict__ kcl,
    __bf16* __restrict__ vch, __bf16* __restrict__ vcl)
{
    const int t    = threadIdx.x;
    const int wave = t >> 6, lane = t & 63;
    const int li   = lane & 15, grp = lane >> 4;
    const int wm   = wave >> 1, wn = wave & 1;
    const int m0   = blockIdx.x * 128;
    const int n0   = blockIdx.y * 128;
    const int z    = blockIdx.z;
    const int bb   = m0 >> 11;
    const int l0   = m0 & (SEQ - 1);
    const int need = (z == 0) ? q_len[bb] : v_len[bb];
    if (l0 >= need) return;

    const __bf16* Xh = Xhi + z * XEL;
    const __bf16* Xl = Xlo + z * XEL;
    const __bf16* Wh = Wchi + z * WEL;
    const __bf16* Wl = Wclo + z * WEL;

    // chunk row bases; chunk (r16, kc) at (r16*32 + kc)*512
    const size_t abase = ((size_t)((m0 >> 4) + wm * 4) * 32) * 512 + lane * 8;
    const size_t bbase = ((size_t)((n0 >> 4) + wn * 4) * 32) * 512 + lane * 8;

    f32x4 acc[4][4] = {};
    bf16x8 ah[2][4], al[2][4], bh[2][4], bl[2][4];

    #pragma unroll
    for (int i = 0; i < 4; ++i) {
        ah[0][i] = *(const bf16x8*)(Xh + abase + (size_t)i * 16384);
        al[0][i] = *(const bf16x8*)(Xl + abase + (size_t)i * 16384);
        bh[0][i] = *(const bf16x8*)(Wh + bbase + (size_t)i * 16384);
        bl[0][i] = *(const bf16x8*)(Wl + bbase + (size_t)i * 16384);
    }

    #pragma unroll 2
    for (int kc = 0; kc < 32; ++kc) {
        const int cur = kc & 1, nxt = cur ^ 1;
        if (kc < 31) {
            const size_t ka = abase + (size_t)(kc + 1) * 512;
            const size_t kb = bbase + (size_t)(kc + 1) * 512;
            #pragma unroll
            for (int i = 0; i < 4; ++i) {
                ah[nxt][i] = *(const bf16x8*)(Xh + ka + (size_t)i * 16384);
                al[nxt][i] = *(const bf16x8*)(Xl + ka + (size_t)i * 16384);
                bh[nxt][i] = *(const bf16x8*)(Wh + kb + (size_t)i * 16384);
                bl[nxt][i] = *(const bf16x8*)(Wl + kb + (size_t)i * 16384);
            }
        }
        #pragma unroll
        for (int j = 0; j < 4; ++j) {
            #pragma unroll
            for (int i = 0; i < 4; ++i) {
                acc[i][j] = __builtin_amdgcn_mfma_f32_16x16x32_bf16(ah[cur][i], bh[cur][j], acc[i][j], 0, 0, 0);
                acc[i][j] = __builtin_amdgcn_mfma_f32_16x16x32_bf16(ah[cur][i], bl[cur][j], acc[i][j], 0, 0, 0);
                acc[i][j] = __builtin_amdgcn_mfma_f32_16x16x32_bf16(al[cur][i], bh[cur][j], acc[i][j], 0, 0, 0);
            }
        }
    }

    // Epilogue: C/D col=li, row=grp*4+r. Write chunk-format outputs.
    #pragma unroll
    for (int j = 0; j < 4; ++j) {
        const int cg = n0 + wn * 64 + j * 16 + li;
        const int hd = cg >> 6, d = cg & 63;
        const int bhI = bb * NB_HEAD + hd;
        #pragma unroll
        for (int i = 0; i < 4; ++i) {
            #pragma unroll
            for (int r = 0; r < 4; ++r) {
                const int rg = m0 + wm * 64 + i * 16 + grp * 4 + r;
                const int lg = rg & (SEQ - 1);
                __bf16 h_, l_;
                split_bf16(acc[i][j][r], h_, l_);
                if (z == 0) {
                    const size_t a = qkelem(bhI, lg, d);
                    qch[a] = h_; qcl[a] = l_;
                } else if (z == 1) {
                    const size_t a = qkelem(bhI, lg, d);
                    kch[a] = h_; kcl[a] = l_;
                } else {
                    const size_t a = velem(bhI, d, lg);
                    vch[a] = h_; vcl[a] = l_;
                }
            }
        }
    }
}

// ---------------------------------------------------------------------------
// Barrier-free MFMA flash attention. Each wave = 32 independent queries.
// K/V fragments load straight from chunk-format global (no LDS staging).
// Only LDS: wave-private P strip (ds_write->lgkmcnt->ds_read).
// ---------------------------------------------------------------------------
__global__ __launch_bounds__(256, 2) void attn_mfma_kernel(
    const __bf16* __restrict__ qch, const __bf16* __restrict__ qcl,
    const __bf16* __restrict__ kch, const __bf16* __restrict__ kcl,
    const __bf16* __restrict__ vch, const __bf16* __restrict__ vcl,
    const int* __restrict__ q_len, const int* __restrict__ v_len,
    float* __restrict__ out)
{
    __shared__ __align__(16) __bf16 Ps[128][72];

    const int t = threadIdx.x;
    const int wq = t >> 6, lane = t & 63;
    const int grp = lane >> 4, li = lane & 15;
    const int hh = blockIdx.x;
    const int q0 = blockIdx.y * 128;
    const int b  = blockIdx.z;
    const int qlen = q_len[b], vlen = v_len[b];
    const int bh = b * NB_HEAD + hh;
    const int qbase = q0 + wq * 32;

    if (qbase >= qlen) {   // wave-level early out: zeros for 32 rows
        const int row = qbase + (lane >> 1), cs = (lane & 1) * 32;
        float* o = out + ((size_t)b * SEQ + row) * D_MODEL + hh * HEAD_DIM + cs;
        const float4 z4 = make_float4(0.f, 0.f, 0.f, 0.f);
        #pragma unroll
        for (int u = 0; u < 8; ++u) *(float4*)(o + u * 4) = z4;
        return;
    }

    // persistent Q fragments
    bf16x8 qh[2][2], ql[2][2];
    #pragma unroll
    for (int s = 0; s < 2; ++s)
        #pragma unroll
        for (int ks = 0; ks < 2; ++ks) {
            const size_t a = qkbase(bh, (qbase >> 4) + s, ks) + lane * 8;
            qh[s][ks] = *(const bf16x8*)(qch + a);
            ql[s][ks] = *(const bf16x8*)(qcl + a);
        }

    f32x4 O[2][4] = {};
    float m_s[2][4], l_s[2][4];
    #pragma unroll
    for (int s = 0; s < 2; ++s)
        #pragma unroll
        for (int r = 0; r < 4; ++r) { m_s[s][r] = -1e30f; l_s[s][r] = 0.f; }

    const int nkt = (vlen + 63) >> 6;

    for (int tt = 0; tt < nkt; ++tt) {
        const int k0 = tt * 64;

        // ---- S = Q K^T (split), K frags direct from global
        f32x4 sacc[2][4] = {};
        #pragma unroll
        for (int ks = 0; ks < 2; ++ks) {
            bf16x8 kh_[4], kl_[4];
            #pragma unroll
            for (int j = 0; j < 4; ++j) {
                const size_t a = qkbase(bh, (k0 >> 4) + j, ks) + lane * 8;
                kh_[j] = *(const bf16x8*)(kch + a);
                kl_[j] = *(const bf16x8*)(kcl + a);
            }
            #pragma unroll
            for (int j = 0; j < 4; ++j)
                #pragma unroll
                for (int s = 0; s < 2; ++s) {
                    sacc[s][j] = __builtin_amdgcn_mfma_f32_16x16x32_bf16(qh[s][ks], kh_[j], sacc[s][j], 0, 0, 0);
                    sacc[s][j] = __builtin_amdgcn_mfma_f32_16x16x32_bf16(qh[s][ks], kl_[j], sacc[s][j], 0, 0, 0);
                    sacc[s][j] = __builtin_amdgcn_mfma_f32_16x16x32_bf16(ql[s][ks], kh_[j], sacc[s][j], 0, 0, 0);
                }
        }

        // ---- issue V frag loads early (hidden behind softmax VALU)
        bf16x8 vh_[2][4], vl_[2][4];
        #pragma unroll
        for (int ks = 0; ks < 2; ++ks)
            #pragma unroll
            for (int j = 0; j < 4; ++j) {
                const size_t a = vbase(bh, j, (k0 >> 5) + ks) + lane * 8;
                vh_[ks][j] = *(const bf16x8*)(vch + a);
                vl_[ks][j] = *(const bf16x8*)(vcl + a);
            }

        // ---- online softmax (C-layout: row=grp*4+r, col=li)
        #pragma unroll
        for (int s = 0; s < 2; ++s) {
            float mx[4] = {-1e30f, -1e30f, -1e30f, -1e30f};
            #pragma unroll
            for (int j = 0; j < 4; ++j) {
                const int key = k0 + j * 16 + li;
                #pragma unroll
                for (int r = 0; r < 4; ++r) {
                    float v = sacc[s][j][r] * 0.125f;
                    if (key >= vlen) v = -1e30f;
                    sacc[s][j][r] = v;
                    mx[r] = fmaxf(mx[r], v);
                }
            }
            #pragma unroll
            for (int r = 0; r < 4; ++r) {
                mx[r] = fmaxf(mx[r], __shfl_xor(mx[r], 1));
                mx[r] = fmaxf(mx[r], __shfl_xor(mx[r], 2));
                mx[r] = fmaxf(mx[r], __shfl_xor(mx[r], 4));
                mx[r] = fmaxf(mx[r], __shfl_xor(mx[r], 8));
            }
            float al[4], sum[4];
            #pragma unroll
            for (int r = 0; r < 4; ++r) {
                const float mn = fmaxf(m_s[s][r], mx[r]);
                al[r] = __expf(m_s[s][r] - mn);
                m_s[s][r] = mn;
                sum[r] = 0.f;
            }
            #pragma unroll
            for (int j = 0; j < 4; ++j)
                #pragma unroll
                for (int r = 0; r < 4; ++r) {
                    const float p = __expf(sacc[s][j][r] - m_s[s][r]);
                    const __bf16 pb = (__bf16)p;   // l sums the ROUNDED p
                    sum[r] += (float)pb;
                    Ps[wq * 32 + s * 16 + grp * 4 + r][j * 16 + li] = pb;
                }
            #pragma unroll
            for (int r = 0; r < 4; ++r) {
                sum[r] += __shfl_xor(sum[r], 1);
                sum[r] += __shfl_xor(sum[r], 2);
                sum[r] += __shfl_xor(sum[r], 4);
                sum[r] += __shfl_xor(sum[r], 8);
                l_s[s][r] = l_s[s][r] * al[r] + sum[r];
            }
            #pragma unroll
            for (int j = 0; j < 4; ++j)
                #pragma unroll
                for (int r = 0; r < 4; ++r) O[s][j][r] *= al[r];
        }
        asm volatile("s_waitcnt lgkmcnt(0)" ::: "memory");  // wave-private P strip

        // ---- O += P V (P single rounded bf16, V split)
        #pragma unroll
        for (int ks = 0; ks < 2; ++ks) {
            bf16x8 pa[2];
            #pragma unroll
            for (int s = 0; s < 2; ++s)
                pa[s] = *(const bf16x8*)&Ps[wq * 32 + s * 16 + li][ks * 32 + grp * 8];
            #pragma unroll
            for (int j = 0; j < 4; ++j)
                #pragma unroll
                for (int s = 0; s < 2; ++s) {
                    O[s][j] = __builtin_amdgcn_mfma_f32_16x16x32_bf16(pa[s], vh_[ks][j], O[s][j], 0, 0, 0);
                    O[s][j] = __builtin_amdgcn_mfma_f32_16x16x32_bf16(pa[s], vl_[ks][j], O[s][j], 0, 0, 0);
                }
        }
    }

    // epilogue
    #pragma unroll
    for (int s = 0; s < 2; ++s)
        #pragma unroll
        for (int r = 0; r < 4; ++r) {
            const int q = qbase + s * 16 + grp * 4 + r;
            const float inv = (q < qlen) ? 1.f / l_s[s][r] : 0.f;
            #pragma unroll
            for (int j = 0; j < 4; ++j)
                out[((size_t)b * SEQ + q) * D_MODEL + hh * HEAD_DIM + j * 16 + li] = O[s][j][r] * inv;
        }
}

extern "C" void kernel_launch(void* const* d_in, const int* in_sizes, int n_in,
                              void* d_out, int out_size, void* d_ws, size_t ws_size,
                              hipStream_t stream)
{
    (void)in_sizes; (void)n_in; (void)out_size; (void)ws_size;
    const float* Q_seq = (const float*)d_in[0];
    const float* K_seq = (const float*)d_in[1];
    const float* V_seq = (const float*)d_in[2];
    const int*   q_len = (const int*)d_in[3];
    const int*   v_len = (const int*)d_in[4];
    const float* WQ    = (const float*)d_in[5];
    const float* WK    = (const float*)d_in[6];
    const float* WV    = (const float*)d_in[7];
    float* out = (float*)d_out;

    // ws (__bf16 elems): W 2x3M, X 2x12M, q/k/v chunks 6x4M = 54M elems = 108 MB
    __bf16* wchi = (__bf16*)d_ws;
    __bf16* wclo = wchi + 3 * WEL;
    __bf16* xhi_ = wclo + 3 * WEL;
    __bf16* xlo_ = xhi_ + 3 * XEL;
    __bf16* qch_ = xlo_ + 3 * XEL;
    __bf16* qcl_ = qch_ + XEL;
    __bf16* kch_ = qcl_ + XEL;
    __bf16* kcl_ = kch_ + XEL;
    __bf16* vch_ = kcl_ + XEL;
    __bf16* vcl_ = vch_ + XEL;

    dim3 blk(256);

    dim3 cg(D_MODEL / 64, D_MODEL / 64, 3);     // (16,16,3)
    conv_wt_kernel<<<cg, blk, 0, stream>>>(WQ, WK, WV, wchi, wclo);

    dim3 xg((unsigned)(XEL / 2048), 3);         // (2048,3)
    conv_x_kernel<<<xg, blk, 0, stream>>>(Q_seq, K_seq, V_seq, q_len, v_len, xhi_, xlo_);

    dim3 pg(MROWS / 128, D_MODEL / 128, 3);     // (32,8,3) = 768
    proj_mfma_kernel<<<pg, blk, 0, stream>>>(xhi_, xlo_, wchi, wclo, q_len, v_len,
                                             qch_, qcl_, kch_, kcl_, vch_, vcl_);

    dim3 ag(NB_HEAD, SEQ / 128, BATCH);         // (16,16,2)
    attn_mfma_kernel<<<ag, blk, 0, stream>>>(qch_, qcl_, kch_, kcl_, vch_, vcl_,
                                             q_len, v_len, out);
}